// Round 12
// baseline (330.128 us; speedup 1.0000x reference)
//
#include <hip/hip_runtime.h>
#include <hip/hip_bf16.h>
#include <stdint.h>

typedef unsigned short u16;
typedef __attribute__((ext_vector_type(8))) __bf16 bf16x8;
typedef __attribute__((ext_vector_type(4))) float f32x4;
typedef __attribute__((ext_vector_type(16))) float f32x16;

#define AS1(p) ((const __attribute__((address_space(1))) void*)(p))
#define AS3(p) ((__attribute__((address_space(3))) void*)(p))

__device__ __forceinline__ u16 f2bf(float f) {
  union { float f; uint32_t u; } c; c.f = f;
  uint32_t u = c.u;
  u += 0x7fffu + ((u >> 16) & 1u);   // RTNE
  return (u16)(u >> 16);
}

__device__ __forceinline__ float exp2_fast(float x) {
  float r; asm("v_exp_f32 %0, %1" : "=v"(r) : "v"(x)); return r;
}

// ---------------- fused cast fp32 -> bf16: 4 streams, one launch ----------------
__global__ __launch_bounds__(256) void cast4_f32_bf16(
    const float4* __restrict__ s0, ushort4* __restrict__ d0, int n0,
    const float4* __restrict__ s1, ushort4* __restrict__ d1, int n1,
    const float4* __restrict__ s2, ushort4* __restrict__ d2, int n2,
    const float4* __restrict__ s3, ushort4* __restrict__ d3, int n3) {
  int bid = blockIdx.x;
  const float4* src; ushort4* dst; int n4, b0, nb;
  if (bid < 512)       { src = s0; dst = d0; n4 = n0; b0 = 0;    nb = 512; }
  else if (bid < 1024) { src = s1; dst = d1; n4 = n1; b0 = 512;  nb = 512; }
  else if (bid < 1152) { src = s2; dst = d2; n4 = n2; b0 = 1024; nb = 128; }
  else                 { src = s3; dst = d3; n4 = n3; b0 = 1152; nb = 256; }
  int stride = nb * 256;
  for (int i = (bid - b0) * 256 + threadIdx.x; i < n4; i += stride) {
    float4 v = src[i];
    ushort4 o;
    o.x = f2bf(v.x); o.y = f2bf(v.y); o.z = f2bf(v.z); o.w = f2bf(v.w);
    dst[i] = o;
  }
}

// ---------------- fused NT GEMM (q + kv), depth-2 prefetch (3 LDS buffers) ----------------
__global__ __launch_bounds__(256) void gemm_fused(const u16* __restrict__ xb,
                                                  const u16* __restrict__ wqb,
                                                  u16* __restrict__ qo,
                                                  const u16* __restrict__ cb,
                                                  const u16* __restrict__ wkb,
                                                  u16* __restrict__ kvo,
                                                  float scale_q) {
  __shared__ u16 As[3][128 * 32];
  __shared__ u16 Bs[3][128 * 32];
  const int K = 1024;
  int bid = (blockIdx.x & 7) * 96 + (blockIdx.x >> 3);
  const u16 *A, *B; u16* C; int N, bm, bn; float scale;
  if (bid < 256) { A = xb; B = wqb; C = qo;  N = 1024; bm = bid >> 3; bn = bid & 7;  scale = scale_q; }
  else { int b2 = bid - 256; A = cb; B = wkb; C = kvo; N = 2048; bm = b2 >> 4; bn = b2 & 15; scale = 1.0f; }

  int tid = threadIdx.x;
  int w = tid >> 6, l = tid & 63;
  int wr = w >> 1, wc = w & 1;
  int lr = l & 15, lg = l >> 4;

  const u16* Abase = A + (size_t)(bm * 128 + (l >> 2)) * K + (l & 3) * 8;
  const u16* Bbase = B + (size_t)(bn * 128 + (l >> 2)) * K + (l & 3) * 8;

  f32x4 acc[4][4];
#pragma unroll
  for (int i = 0; i < 4; ++i)
#pragma unroll
    for (int j = 0; j < 4; ++j) acc[i][j] = (f32x4){0.f, 0.f, 0.f, 0.f};

#define STAGE(buf, k0)                                                              \
  {                                                                                 \
    _Pragma("unroll")                                                               \
    for (int t2 = 0; t2 < 2; ++t2) {                                                \
      int seg = w * 2 + t2;                                                         \
      __builtin_amdgcn_global_load_lds(AS1(Abase + (size_t)seg * 16 * K + (k0)),    \
                                       AS3(&As[buf][seg * 512]), 16, 0, 0);         \
      __builtin_amdgcn_global_load_lds(AS1(Bbase + (size_t)seg * 16 * K + (k0)),    \
                                       AS3(&Bs[buf][seg * 512]), 16, 0, 0);         \
    }                                                                               \
  }

  STAGE(0, 0);
  STAGE(1, 32);
  int cur = 0;
  for (int t = 0; t < 32; ++t) {
    if (t < 30) {
      int pf = cur + 2; if (pf >= 3) pf -= 3;
      STAGE(pf, (t + 2) * 32);
      asm volatile("s_waitcnt vmcnt(8)" ::: "memory");
    } else if (t == 30) {
      asm volatile("s_waitcnt vmcnt(4)" ::: "memory");
    } else {
      asm volatile("s_waitcnt vmcnt(0)" ::: "memory");
    }
    __builtin_amdgcn_s_barrier();
    bf16x8 af[4], bb[4];
#pragma unroll
    for (int i = 0; i < 4; ++i)
      af[i] = *(const bf16x8*)(&As[cur][(wr * 64 + i * 16 + lr) * 32 + lg * 8]);
#pragma unroll
    for (int j = 0; j < 4; ++j)
      bb[j] = *(const bf16x8*)(&Bs[cur][(wc * 64 + j * 16 + lr) * 32 + lg * 8]);
    asm volatile("s_waitcnt lgkmcnt(0)" ::: "memory");
    __builtin_amdgcn_sched_barrier(0);
#pragma unroll
    for (int i = 0; i < 4; ++i)
#pragma unroll
      for (int j = 0; j < 4; ++j)
        acc[i][j] = __builtin_amdgcn_mfma_f32_16x16x32_bf16(af[i], bb[j], acc[i][j], 0, 0, 0);
    __builtin_amdgcn_s_barrier();
    if (++cur == 3) cur = 0;
  }
#undef STAGE

#pragma unroll
  for (int i = 0; i < 4; ++i)
#pragma unroll
    for (int j = 0; j < 4; ++j)
#pragma unroll
      for (int r = 0; r < 4; ++r) {
        int row = bm * 128 + wr * 64 + i * 16 + lg * 4 + r;
        int col = bn * 128 + wc * 64 + j * 16 + lr;
        C[(size_t)row * N + col] = f2bf(acc[i][j][r] * scale);
      }
}

// ---------------- flash attention: KVBLK=128, single-buffer Vt, ones-MFMA row-sum ----------------
// grid = 512 blocks (3/CU at 48KB LDS), 256 thr (4 waves x 32 q-rows).
// Vt single-buffered (PV reads it same-iteration; next write is after next top barrier).
// l accumulated via accS = mfma(ones, P, accS) on the matrix pipe — no VALU sum, no shuffle.
#define SQ 2048
#define NTT 16

__global__ __launch_bounds__(256, 3) void attn_kernel(const u16* __restrict__ Q,
                                                      const u16* __restrict__ KV,
                                                      float* __restrict__ O) {
  __shared__ u16 Ks[2][128 * 64];  // [buf][j][d], 16B-block bk holds dblk = bk ^ (j&7)  32KB
  __shared__ u16 Vt[64 * 128];     // [d][j], byte = d*256 + ((j*2) ^ (((d^(d>>3))&7)<<4)) 16KB

  int wgid = (blockIdx.x & 7) * 64 + (blockIdx.x >> 3);   // bijective 8x64 XCD swizzle
  int qt = wgid & 15;
  int bh = wgid >> 4;
  int b = bh >> 4, h = bh & 15;
  int tid = threadIdx.x;
  int w = tid >> 6, l = tid & 63;
  int li = l & 31, hi = l >> 5;
  int jr = l >> 3, bk = l & 7;
  int a7 = tid & 7, jj = tid >> 3;   // V staging coords

  const u16* kbase = KV + (size_t)b * SQ * 2048 + (size_t)h * 64;
  const u16* vbase = kbase + 1024;
  int i0g = qt * 128 + w * 32;
  const u16* qrow = Q + (size_t)(b * SQ + i0g + li) * 1024 + h * 64;

  bf16x8 qf0 = *(const bf16x8*)(qrow + 0  + hi * 8);
  bf16x8 qf1 = *(const bf16x8*)(qrow + 16 + hi * 8);
  bf16x8 qf2 = *(const bf16x8*)(qrow + 32 + hi * 8);
  bf16x8 qf3 = *(const bf16x8*)(qrow + 48 + hi * 8);

  union { u16 u[8]; bf16x8 v; } onesu;
#pragma unroll
  for (int e = 0; e < 8; ++e) onesu.u[e] = 0x3F80;   // bf16 1.0
  bf16x8 ones = onesu.v;

  // prologue: stage K tile 0 (128 rows, 4 gload_lds/thread); V tile 0 -> regs
#pragma unroll
  for (int c = 0; c < 4; ++c) {
    const u16* gk = kbase + (size_t)(c * 32 + w * 8 + jr) * 2048 + ((bk ^ jr) * 8);
    __builtin_amdgcn_global_load_lds(AS1(gk), AS3(&Ks[0][c * 2048 + w * 512]), 16, 0, 0);
  }
  uint4 vrA = *(const uint4*)(vbase + (size_t)(jj +  0) * 2048 + a7 * 8);
  uint4 vrB = *(const uint4*)(vbase + (size_t)(jj + 32) * 2048 + a7 * 8);
  uint4 vrC = *(const uint4*)(vbase + (size_t)(jj + 64) * 2048 + a7 * 8);
  uint4 vrD = *(const uint4*)(vbase + (size_t)(jj + 96) * 2048 + a7 * 8);

  float m_run = -1e30f;
  f32x16 acc0, acc1, accS, zz;
#pragma unroll
  for (int r = 0; r < 16; ++r) { acc0[r] = 0.f; acc1[r] = 0.f; accS[r] = 0.f; zz[r] = 0.f; }

  int swk = (li & 7) << 4;
  int sw0 = ((li ^ (li >> 3)) & 7) << 4;                 // Vt read swizzle, d = li
  int sw1 = (((32 + li) ^ ((32 + li) >> 3)) & 7) << 4;   // d = 32+li

  for (int t = 0; t < NTT; ++t) {
    u16* Ksc = (u16*)Ks[t & 1];
    char* Vtc = (char*)Vt;
    __syncthreads();   // K(t),V(t) landed (vmcnt drain); all waves' PV(t-1) reads of Vt done
    // ---- V transpose-store: 32 scalar b16 (2-way bank max)
    {
      const u16* pA = (const u16*)&vrA;
      const u16* pB = (const u16*)&vrB;
      const u16* pC = (const u16*)&vrC;
      const u16* pD = (const u16*)&vrD;
#pragma unroll
      for (int e = 0; e < 8; ++e) {
        int dbyte = (a7 * 8 + e) * 256, sw = (e ^ a7) << 4;
        *(u16*)(Vtc + dbyte + (((jj * 2) +   0) ^ sw)) = pA[e];
        *(u16*)(Vtc + dbyte + (((jj * 2) +  64) ^ sw)) = pB[e];
        *(u16*)(Vtc + dbyte + (((jj * 2) + 128) ^ sw)) = pC[e];
        *(u16*)(Vtc + dbyte + (((jj * 2) + 192) ^ sw)) = pD[e];
      }
    }
    asm volatile("s_waitcnt lgkmcnt(0)" ::: "memory");   // my ds_writes committed
    __builtin_amdgcn_s_barrier();                        // Vt visible (no vmcnt drain)
    // ---- prefetch tile t+1 (rides through compute; drained by next top-sync)
    if (t + 1 < NTT) {
      int j0n = (t + 1) * 128;
      u16* Ksn = (u16*)Ks[(t + 1) & 1];
#pragma unroll
      for (int c = 0; c < 4; ++c) {
        const u16* gk = kbase + (size_t)(j0n + c * 32 + w * 8 + jr) * 2048 + ((bk ^ jr) * 8);
        __builtin_amdgcn_global_load_lds(AS1(gk), AS3(&Ksn[c * 2048 + w * 512]), 16, 0, 0);
      }
      vrA = *(const uint4*)(vbase + (size_t)(j0n + jj +  0) * 2048 + a7 * 8);
      vrB = *(const uint4*)(vbase + (size_t)(j0n + jj + 32) * 2048 + a7 * 8);
      vrC = *(const uint4*)(vbase + (size_t)(j0n + jj + 64) * 2048 + a7 * 8);
      vrD = *(const uint4*)(vbase + (size_t)(j0n + jj + 96) * 2048 + a7 * 8);
    }
    // ---- swapped QK^T: 16 MFMAs, 4 independent chains
    f32x16 s0, s1, s2, s3;
    __builtin_amdgcn_s_setprio(1);
#define QKT1(sv, JB)                                                             \
    {                                                                            \
      const char* kr = (const char*)Ksc + ((JB) * 32 + li) * 128;                \
      bf16x8 kk;                                                                 \
      kk = *(const bf16x8*)(kr + ((0  + hi * 16) ^ swk));                        \
      sv = __builtin_amdgcn_mfma_f32_32x32x16_bf16(kk, qf0, zz, 0, 0, 0);        \
      kk = *(const bf16x8*)(kr + ((32 + hi * 16) ^ swk));                        \
      sv = __builtin_amdgcn_mfma_f32_32x32x16_bf16(kk, qf1, sv, 0, 0, 0);        \
      kk = *(const bf16x8*)(kr + ((64 + hi * 16) ^ swk));                        \
      sv = __builtin_amdgcn_mfma_f32_32x32x16_bf16(kk, qf2, sv, 0, 0, 0);        \
      kk = *(const bf16x8*)(kr + ((96 + hi * 16) ^ swk));                        \
      sv = __builtin_amdgcn_mfma_f32_32x32x16_bf16(kk, qf3, sv, 0, 0, 0);        \
    }
    QKT1(s0, 0)
    QKT1(s1, 1)
    QKT1(s2, 2)
    QKT1(s3, 3)
#undef QKT1
    __builtin_amdgcn_s_setprio(0);
    // ---- ONE max-reduce over 64 values (v_max3-friendly pairs)
    float pm = fmaxf(s0[14], s0[15]);
#pragma unroll
    for (int r = 0; r < 14; r += 2) pm = fmaxf(fmaxf(pm, s0[r]), s0[r + 1]);
#pragma unroll
    for (int r = 0; r < 16; r += 2) pm = fmaxf(fmaxf(pm, s1[r]), s1[r + 1]);
#pragma unroll
    for (int r = 0; r < 16; r += 2) pm = fmaxf(fmaxf(pm, s2[r]), s2[r + 1]);
#pragma unroll
    for (int r = 0; r < 16; r += 2) pm = fmaxf(fmaxf(pm, s3[r]), s3[r + 1]);
    pm = fmaxf(pm, __shfl_xor(pm, 32));
    if (!__all(pm <= m_run + 8.0f)) {
      float mnew = fmaxf(m_run, pm);
      float esc = exp2_fast(m_run - mnew);
      m_run = mnew;
      accS[0] *= esc;   // only reg 0 of accS is ever read
#pragma unroll
      for (int r = 0; r < 16; ++r) { acc0[r] *= esc; acc1[r] *= esc; }
    }
    // ---- exp in place (64 independent; no sum chain — accS handles l)
#pragma unroll
    for (int r = 0; r < 16; ++r) s0[r] = exp2_fast(s0[r] - m_run);
#pragma unroll
    for (int r = 0; r < 16; ++r) s1[r] = exp2_fast(s1[r] - m_run);
#pragma unroll
    for (int r = 0; r < 16; ++r) s2[r] = exp2_fast(s2[r] - m_run);
#pragma unroll
    for (int r = 0; r < 16; ++r) s3[r] = exp2_fast(s3[r] - m_run);
    // ---- pack P -> bf16 A-frag layout (cvt_pk + permlane32_swap), 4 groups of 8 words
    unsigned pw[32];
#pragma unroll
    for (int i2 = 0; i2 < 8; ++i2) {
      asm("v_cvt_pk_bf16_f32 %0, %1, %2" : "=v"(pw[i2])      : "v"(s0[2 * i2]), "v"(s0[2 * i2 + 1]));
      asm("v_cvt_pk_bf16_f32 %0, %1, %2" : "=v"(pw[8 + i2])  : "v"(s1[2 * i2]), "v"(s1[2 * i2 + 1]));
      asm("v_cvt_pk_bf16_f32 %0, %1, %2" : "=v"(pw[16 + i2]) : "v"(s2[2 * i2]), "v"(s2[2 * i2 + 1]));
      asm("v_cvt_pk_bf16_f32 %0, %1, %2" : "=v"(pw[24 + i2]) : "v"(s3[2 * i2]), "v"(s3[2 * i2 + 1]));
    }
#pragma unroll
    for (int gB = 0; gB < 4; ++gB) {
      int o = gB * 8;
      asm volatile("v_permlane32_swap_b32 %0, %1" : "+v"(pw[o + 0]), "+v"(pw[o + 2]));
      asm volatile("v_permlane32_swap_b32 %0, %1" : "+v"(pw[o + 1]), "+v"(pw[o + 3]));
      asm volatile("v_permlane32_swap_b32 %0, %1" : "+v"(pw[o + 4]), "+v"(pw[o + 6]));
      asm volatile("v_permlane32_swap_b32 %0, %1" : "+v"(pw[o + 5]), "+v"(pw[o + 7]));
    }
    // ---- PV as O^T (16 MFMAs) + row-sum accS (8 MFMAs, A=ones)
    __builtin_amdgcn_s_setprio(1);
#pragma unroll
    for (int jsp = 0; jsp < 8; ++jsp) {
      uint4 ufr;
      ufr.x = pw[jsp * 4 + 0]; ufr.y = pw[jsp * 4 + 1];
      ufr.z = pw[jsp * 4 + 2]; ufr.w = pw[jsp * 4 + 3];
      bf16x8 pa = *(bf16x8*)&ufr;
      int jbyte = jsp * 32 + hi * 16;
      bf16x8 v0 = *(const bf16x8*)(Vtc + li * 256 + (jbyte ^ sw0));
      bf16x8 v1 = *(const bf16x8*)(Vtc + (32 + li) * 256 + (jbyte ^ sw1));
      acc0 = __builtin_amdgcn_mfma_f32_32x32x16_bf16(v0, pa, acc0, 0, 0, 0);
      acc1 = __builtin_amdgcn_mfma_f32_32x32x16_bf16(v1, pa, acc1, 0, 0, 0);
      accS = __builtin_amdgcn_mfma_f32_32x32x16_bf16(ones, pa, accS, 0, 0, 0);
    }
    __builtin_amdgcn_s_setprio(0);
  }
  // ---- epilogue: O^T layout, d = 8g + 4hi + r (+32 for acc1), col(q-row) = li
  float inv = 1.f / accS[0];
  float* orow = O + ((size_t)(b * SQ + i0g + li) * 1024 + h * 64);
#pragma unroll
  for (int g = 0; g < 4; ++g) {
    f32x4 o0, o1;
#pragma unroll
    for (int q_ = 0; q_ < 4; ++q_) {
      o0[q_] = acc0[g * 4 + q_] * inv;
      o1[q_] = acc1[g * 4 + q_] * inv;
    }
    *(f32x4*)(orow + 8 * g + 4 * hi) = o0;
    *(f32x4*)(orow + 32 + 8 * g + 4 * hi) = o1;
  }
}

extern "C" void kernel_launch(void* const* d_in, const int* in_sizes, int n_in,
                              void* d_out, int out_size, void* d_ws, size_t ws_size,
                              hipStream_t stream) {
  (void)in_sizes; (void)n_in; (void)out_size; (void)ws_size;
  const float* x   = (const float*)d_in[0];
  const float* ctx = (const float*)d_in[1];
  const float* Wq  = (const float*)d_in[2];
  const float* Wkv = (const float*)d_in[3];
  float* out = (float*)d_out;
  char* ws = (char*)d_ws;

  u16* xb  = (u16*)(ws);                       // x bf16   [4096][1024]  8 MB
  u16* cb  = (u16*)(ws + (8ull  << 20));       // ctx bf16 [4096][1024]  8 MB
  u16* wqb = (u16*)(ws + (16ull << 20));       // Wq bf16  [1024][1024]  2 MB
  u16* wkb = (u16*)(ws + (18ull << 20));       // Wkv bf16 [2048][1024]  4 MB
  u16* q   = (u16*)(ws + (22ull << 20));       // q bf16, pre-scaled by 0.125*log2(e)
  u16* kv  = (u16*)(ws + (30ull << 20));       // kv bf16  [4096][2048] 16 MB

  cast4_f32_bf16<<<1408, 256, 0, stream>>>(
      (const float4*)x,   (ushort4*)xb,  (4096 * 1024) / 4,
      (const float4*)ctx, (ushort4*)cb,  (4096 * 1024) / 4,
      (const float4*)Wq,  (ushort4*)wqb, (1024 * 1024) / 4,
      (const float4*)Wkv, (ushort4*)wkb, (2048 * 1024) / 4);

  gemm_fused<<<768, 256, 0, stream>>>(xb, wqb, q, cb, wkb, kv, 0.125f * 1.44269504f);

  attn_kernel<<<512, 256, 0, stream>>>(q, kv, out);
}

// Round 13
// 99.717 us; speedup vs baseline: 3.3106x; 3.3106x over previous
//
#include <hip/hip_runtime.h>
#include <hip/hip_bf16.h>
#include <stdint.h>

typedef unsigned short u16;
typedef __attribute__((ext_vector_type(8))) __bf16 bf16x8;
typedef __attribute__((ext_vector_type(4))) float f32x4;
typedef __attribute__((ext_vector_type(16))) float f32x16;

#define AS1(p) ((const __attribute__((address_space(1))) void*)(p))
#define AS3(p) ((__attribute__((address_space(3))) void*)(p))

__device__ __forceinline__ u16 f2bf(float f) {
  union { float f; uint32_t u; } c; c.f = f;
  uint32_t u = c.u;
  u += 0x7fffu + ((u >> 16) & 1u);   // RTNE
  return (u16)(u >> 16);
}

__device__ __forceinline__ float exp2_fast(float x) {
  float r; asm("v_exp_f32 %0, %1" : "=v"(r) : "v"(x)); return r;
}

// ---------------- fused cast fp32 -> bf16: 4 streams, one launch ----------------
__global__ __launch_bounds__(256) void cast4_f32_bf16(
    const float4* __restrict__ s0, ushort4* __restrict__ d0, int n0,
    const float4* __restrict__ s1, ushort4* __restrict__ d1, int n1,
    const float4* __restrict__ s2, ushort4* __restrict__ d2, int n2,
    const float4* __restrict__ s3, ushort4* __restrict__ d3, int n3) {
  int bid = blockIdx.x;
  const float4* src; ushort4* dst; int n4, b0, nb;
  if (bid < 512)       { src = s0; dst = d0; n4 = n0; b0 = 0;    nb = 512; }
  else if (bid < 1024) { src = s1; dst = d1; n4 = n1; b0 = 512;  nb = 512; }
  else if (bid < 1152) { src = s2; dst = d2; n4 = n2; b0 = 1024; nb = 128; }
  else                 { src = s3; dst = d3; n4 = n3; b0 = 1152; nb = 256; }
  int stride = nb * 256;
  for (int i = (bid - b0) * 256 + threadIdx.x; i < n4; i += stride) {
    float4 v = src[i];
    ushort4 o;
    o.x = f2bf(v.x); o.y = f2bf(v.y); o.z = f2bf(v.z); o.w = f2bf(v.w);
    dst[i] = o;
  }
}

// ---------------- fused NT GEMM (q + kv), depth-2 prefetch (3 LDS buffers) ----------------
__global__ __launch_bounds__(256) void gemm_fused(const u16* __restrict__ xb,
                                                  const u16* __restrict__ wqb,
                                                  u16* __restrict__ qo,
                                                  const u16* __restrict__ cb,
                                                  const u16* __restrict__ wkb,
                                                  u16* __restrict__ kvo,
                                                  float scale_q) {
  __shared__ u16 As[3][128 * 32];
  __shared__ u16 Bs[3][128 * 32];
  const int K = 1024;
  int bid = (blockIdx.x & 7) * 96 + (blockIdx.x >> 3);
  const u16 *A, *B; u16* C; int N, bm, bn; float scale;
  if (bid < 256) { A = xb; B = wqb; C = qo;  N = 1024; bm = bid >> 3; bn = bid & 7;  scale = scale_q; }
  else { int b2 = bid - 256; A = cb; B = wkb; C = kvo; N = 2048; bm = b2 >> 4; bn = b2 & 15; scale = 1.0f; }

  int tid = threadIdx.x;
  int w = tid >> 6, l = tid & 63;
  int wr = w >> 1, wc = w & 1;
  int lr = l & 15, lg = l >> 4;

  const u16* Abase = A + (size_t)(bm * 128 + (l >> 2)) * K + (l & 3) * 8;
  const u16* Bbase = B + (size_t)(bn * 128 + (l >> 2)) * K + (l & 3) * 8;

  f32x4 acc[4][4];
#pragma unroll
  for (int i = 0; i < 4; ++i)
#pragma unroll
    for (int j = 0; j < 4; ++j) acc[i][j] = (f32x4){0.f, 0.f, 0.f, 0.f};

#define STAGE(buf, k0)                                                              \
  {                                                                                 \
    _Pragma("unroll")                                                               \
    for (int t2 = 0; t2 < 2; ++t2) {                                                \
      int seg = w * 2 + t2;                                                         \
      __builtin_amdgcn_global_load_lds(AS1(Abase + (size_t)seg * 16 * K + (k0)),    \
                                       AS3(&As[buf][seg * 512]), 16, 0, 0);         \
      __builtin_amdgcn_global_load_lds(AS1(Bbase + (size_t)seg * 16 * K + (k0)),    \
                                       AS3(&Bs[buf][seg * 512]), 16, 0, 0);         \
    }                                                                               \
  }

  STAGE(0, 0);
  STAGE(1, 32);
  int cur = 0;
  for (int t = 0; t < 32; ++t) {
    if (t < 30) {
      int pf = cur + 2; if (pf >= 3) pf -= 3;
      STAGE(pf, (t + 2) * 32);
      asm volatile("s_waitcnt vmcnt(8)" ::: "memory");
    } else if (t == 30) {
      asm volatile("s_waitcnt vmcnt(4)" ::: "memory");
    } else {
      asm volatile("s_waitcnt vmcnt(0)" ::: "memory");
    }
    __builtin_amdgcn_s_barrier();
    bf16x8 af[4], bb[4];
#pragma unroll
    for (int i = 0; i < 4; ++i)
      af[i] = *(const bf16x8*)(&As[cur][(wr * 64 + i * 16 + lr) * 32 + lg * 8]);
#pragma unroll
    for (int j = 0; j < 4; ++j)
      bb[j] = *(const bf16x8*)(&Bs[cur][(wc * 64 + j * 16 + lr) * 32 + lg * 8]);
    asm volatile("s_waitcnt lgkmcnt(0)" ::: "memory");
    __builtin_amdgcn_sched_barrier(0);
#pragma unroll
    for (int i = 0; i < 4; ++i)
#pragma unroll
      for (int j = 0; j < 4; ++j)
        acc[i][j] = __builtin_amdgcn_mfma_f32_16x16x32_bf16(af[i], bb[j], acc[i][j], 0, 0, 0);
    __builtin_amdgcn_s_barrier();
    if (++cur == 3) cur = 0;
  }
#undef STAGE

#pragma unroll
  for (int i = 0; i < 4; ++i)
#pragma unroll
    for (int j = 0; j < 4; ++j)
#pragma unroll
      for (int r = 0; r < 4; ++r) {
        int row = bm * 128 + wr * 64 + i * 16 + lg * 4 + r;
        int col = bn * 128 + wc * 64 + j * 16 + lr;
        C[(size_t)row * N + col] = f2bf(acc[i][j][r] * scale);
      }
}

// ---------------- flash attention: KVBLK=128, single-buffer Vt, ones-MFMA row-sum ----------------
// grid = 512 blocks, 256 thr (4 waves x 32 q-rows). __launch_bounds__(256,2): the live set
// (~200 unified VGPR+AGPR) requires the 256-reg budget — (256,3) spills catastrophically (r12).
#define SQ 2048
#define NTT 16

__global__ __launch_bounds__(256, 2) void attn_kernel(const u16* __restrict__ Q,
                                                      const u16* __restrict__ KV,
                                                      float* __restrict__ O) {
  __shared__ u16 Ks[2][128 * 64];  // [buf][j][d], 16B-block bk holds dblk = bk ^ (j&7)  32KB
  __shared__ u16 Vt[64 * 128];     // [d][j], byte = d*256 + ((j*2) ^ (((d^(d>>3))&7)<<4)) 16KB

  int wgid = (blockIdx.x & 7) * 64 + (blockIdx.x >> 3);   // bijective 8x64 XCD swizzle
  int qt = wgid & 15;
  int bh = wgid >> 4;
  int b = bh >> 4, h = bh & 15;
  int tid = threadIdx.x;
  int w = tid >> 6, l = tid & 63;
  int li = l & 31, hi = l >> 5;
  int jr = l >> 3, bk = l & 7;
  int a7 = tid & 7, jj = tid >> 3;   // V staging coords

  const u16* kbase = KV + (size_t)b * SQ * 2048 + (size_t)h * 64;
  const u16* vbase = kbase + 1024;
  int i0g = qt * 128 + w * 32;
  const u16* qrow = Q + (size_t)(b * SQ + i0g + li) * 1024 + h * 64;

  bf16x8 qf0 = *(const bf16x8*)(qrow + 0  + hi * 8);
  bf16x8 qf1 = *(const bf16x8*)(qrow + 16 + hi * 8);
  bf16x8 qf2 = *(const bf16x8*)(qrow + 32 + hi * 8);
  bf16x8 qf3 = *(const bf16x8*)(qrow + 48 + hi * 8);

  union { u16 u[8]; bf16x8 v; } onesu;
#pragma unroll
  for (int e = 0; e < 8; ++e) onesu.u[e] = 0x3F80;   // bf16 1.0
  bf16x8 ones = onesu.v;

  // prologue: stage K tile 0 (128 rows, 4 gload_lds/thread); V tile 0 -> regs
#pragma unroll
  for (int c = 0; c < 4; ++c) {
    const u16* gk = kbase + (size_t)(c * 32 + w * 8 + jr) * 2048 + ((bk ^ jr) * 8);
    __builtin_amdgcn_global_load_lds(AS1(gk), AS3(&Ks[0][c * 2048 + w * 512]), 16, 0, 0);
  }
  uint4 vrA = *(const uint4*)(vbase + (size_t)(jj +  0) * 2048 + a7 * 8);
  uint4 vrB = *(const uint4*)(vbase + (size_t)(jj + 32) * 2048 + a7 * 8);
  uint4 vrC = *(const uint4*)(vbase + (size_t)(jj + 64) * 2048 + a7 * 8);
  uint4 vrD = *(const uint4*)(vbase + (size_t)(jj + 96) * 2048 + a7 * 8);

  float m_run = -1e30f;
  f32x16 acc0, acc1, accS, zz;
#pragma unroll
  for (int r = 0; r < 16; ++r) { acc0[r] = 0.f; acc1[r] = 0.f; accS[r] = 0.f; zz[r] = 0.f; }

  int swk = (li & 7) << 4;
  int sw0 = ((li ^ (li >> 3)) & 7) << 4;                 // Vt read swizzle, d = li
  int sw1 = (((32 + li) ^ ((32 + li) >> 3)) & 7) << 4;   // d = 32+li

  for (int t = 0; t < NTT; ++t) {
    u16* Ksc = (u16*)Ks[t & 1];
    char* Vtc = (char*)Vt;
    __syncthreads();   // K(t),V(t) landed (vmcnt drain); all waves' PV(t-1) reads of Vt done
    // ---- V transpose-store: 32 scalar b16 (2-way bank max)
    {
      const u16* pA = (const u16*)&vrA;
      const u16* pB = (const u16*)&vrB;
      const u16* pC = (const u16*)&vrC;
      const u16* pD = (const u16*)&vrD;
#pragma unroll
      for (int e = 0; e < 8; ++e) {
        int dbyte = (a7 * 8 + e) * 256, sw = (e ^ a7) << 4;
        *(u16*)(Vtc + dbyte + (((jj * 2) +   0) ^ sw)) = pA[e];
        *(u16*)(Vtc + dbyte + (((jj * 2) +  64) ^ sw)) = pB[e];
        *(u16*)(Vtc + dbyte + (((jj * 2) + 128) ^ sw)) = pC[e];
        *(u16*)(Vtc + dbyte + (((jj * 2) + 192) ^ sw)) = pD[e];
      }
    }
    asm volatile("s_waitcnt lgkmcnt(0)" ::: "memory");   // my ds_writes committed
    __builtin_amdgcn_s_barrier();                        // Vt visible (no vmcnt drain)
    // ---- prefetch tile t+1 (rides through compute; drained by next top-sync)
    if (t + 1 < NTT) {
      int j0n = (t + 1) * 128;
      u16* Ksn = (u16*)Ks[(t + 1) & 1];
#pragma unroll
      for (int c = 0; c < 4; ++c) {
        const u16* gk = kbase + (size_t)(j0n + c * 32 + w * 8 + jr) * 2048 + ((bk ^ jr) * 8);
        __builtin_amdgcn_global_load_lds(AS1(gk), AS3(&Ksn[c * 2048 + w * 512]), 16, 0, 0);
      }
      vrA = *(const uint4*)(vbase + (size_t)(j0n + jj +  0) * 2048 + a7 * 8);
      vrB = *(const uint4*)(vbase + (size_t)(j0n + jj + 32) * 2048 + a7 * 8);
      vrC = *(const uint4*)(vbase + (size_t)(j0n + jj + 64) * 2048 + a7 * 8);
      vrD = *(const uint4*)(vbase + (size_t)(j0n + jj + 96) * 2048 + a7 * 8);
    }
    // ---- swapped QK^T: 16 MFMAs, 4 independent chains
    f32x16 s0, s1, s2, s3;
    __builtin_amdgcn_s_setprio(1);
#define QKT1(sv, JB)                                                             \
    {                                                                            \
      const char* kr = (const char*)Ksc + ((JB) * 32 + li) * 128;                \
      bf16x8 kk;                                                                 \
      kk = *(const bf16x8*)(kr + ((0  + hi * 16) ^ swk));                        \
      sv = __builtin_amdgcn_mfma_f32_32x32x16_bf16(kk, qf0, zz, 0, 0, 0);        \
      kk = *(const bf16x8*)(kr + ((32 + hi * 16) ^ swk));                        \
      sv = __builtin_amdgcn_mfma_f32_32x32x16_bf16(kk, qf1, sv, 0, 0, 0);        \
      kk = *(const bf16x8*)(kr + ((64 + hi * 16) ^ swk));                        \
      sv = __builtin_amdgcn_mfma_f32_32x32x16_bf16(kk, qf2, sv, 0, 0, 0);        \
      kk = *(const bf16x8*)(kr + ((96 + hi * 16) ^ swk));                        \
      sv = __builtin_amdgcn_mfma_f32_32x32x16_bf16(kk, qf3, sv, 0, 0, 0);        \
    }
    QKT1(s0, 0)
    QKT1(s1, 1)
    QKT1(s2, 2)
    QKT1(s3, 3)
#undef QKT1
    __builtin_amdgcn_s_setprio(0);
    // ---- ONE max-reduce over 64 values (v_max3-friendly pairs)
    float pm = fmaxf(s0[14], s0[15]);
#pragma unroll
    for (int r = 0; r < 14; r += 2) pm = fmaxf(fmaxf(pm, s0[r]), s0[r + 1]);
#pragma unroll
    for (int r = 0; r < 16; r += 2) pm = fmaxf(fmaxf(pm, s1[r]), s1[r + 1]);
#pragma unroll
    for (int r = 0; r < 16; r += 2) pm = fmaxf(fmaxf(pm, s2[r]), s2[r + 1]);
#pragma unroll
    for (int r = 0; r < 16; r += 2) pm = fmaxf(fmaxf(pm, s3[r]), s3[r + 1]);
    pm = fmaxf(pm, __shfl_xor(pm, 32));
    if (!__all(pm <= m_run + 8.0f)) {
      float mnew = fmaxf(m_run, pm);
      float esc = exp2_fast(m_run - mnew);
      m_run = mnew;
      accS[0] *= esc;   // only reg 0 of accS is ever read
#pragma unroll
      for (int r = 0; r < 16; ++r) { acc0[r] *= esc; acc1[r] *= esc; }
    }
    // ---- exp in place (64 independent; no sum chain — accS handles l)
#pragma unroll
    for (int r = 0; r < 16; ++r) s0[r] = exp2_fast(s0[r] - m_run);
#pragma unroll
    for (int r = 0; r < 16; ++r) s1[r] = exp2_fast(s1[r] - m_run);
#pragma unroll
    for (int r = 0; r < 16; ++r) s2[r] = exp2_fast(s2[r] - m_run);
#pragma unroll
    for (int r = 0; r < 16; ++r) s3[r] = exp2_fast(s3[r] - m_run);
    // ---- pack P -> bf16 A-frag layout (cvt_pk + permlane32_swap), 4 groups of 8 words
    unsigned pw[32];
#pragma unroll
    for (int i2 = 0; i2 < 8; ++i2) {
      asm("v_cvt_pk_bf16_f32 %0, %1, %2" : "=v"(pw[i2])      : "v"(s0[2 * i2]), "v"(s0[2 * i2 + 1]));
      asm("v_cvt_pk_bf16_f32 %0, %1, %2" : "=v"(pw[8 + i2])  : "v"(s1[2 * i2]), "v"(s1[2 * i2 + 1]));
      asm("v_cvt_pk_bf16_f32 %0, %1, %2" : "=v"(pw[16 + i2]) : "v"(s2[2 * i2]), "v"(s2[2 * i2 + 1]));
      asm("v_cvt_pk_bf16_f32 %0, %1, %2" : "=v"(pw[24 + i2]) : "v"(s3[2 * i2]), "v"(s3[2 * i2 + 1]));
    }
#pragma unroll
    for (int gB = 0; gB < 4; ++gB) {
      int o = gB * 8;
      asm volatile("v_permlane32_swap_b32 %0, %1" : "+v"(pw[o + 0]), "+v"(pw[o + 2]));
      asm volatile("v_permlane32_swap_b32 %0, %1" : "+v"(pw[o + 1]), "+v"(pw[o + 3]));
      asm volatile("v_permlane32_swap_b32 %0, %1" : "+v"(pw[o + 4]), "+v"(pw[o + 6]));
      asm volatile("v_permlane32_swap_b32 %0, %1" : "+v"(pw[o + 5]), "+v"(pw[o + 7]));
    }
    // ---- PV as O^T (16 MFMAs) + row-sum accS (8 MFMAs, A=ones)
    __builtin_amdgcn_s_setprio(1);
#pragma unroll
    for (int jsp = 0; jsp < 8; ++jsp) {
      uint4 ufr;
      ufr.x = pw[jsp * 4 + 0]; ufr.y = pw[jsp * 4 + 1];
      ufr.z = pw[jsp * 4 + 2]; ufr.w = pw[jsp * 4 + 3];
      bf16x8 pa = *(bf16x8*)&ufr;
      int jbyte = jsp * 32 + hi * 16;
      bf16x8 v0 = *(const bf16x8*)(Vtc + li * 256 + (jbyte ^ sw0));
      bf16x8 v1 = *(const bf16x8*)(Vtc + (32 + li) * 256 + (jbyte ^ sw1));
      acc0 = __builtin_amdgcn_mfma_f32_32x32x16_bf16(v0, pa, acc0, 0, 0, 0);
      acc1 = __builtin_amdgcn_mfma_f32_32x32x16_bf16(v1, pa, acc1, 0, 0, 0);
      accS = __builtin_amdgcn_mfma_f32_32x32x16_bf16(ones, pa, accS, 0, 0, 0);
    }
    __builtin_amdgcn_s_setprio(0);
  }
  // ---- epilogue: O^T layout, d = 8g + 4hi + r (+32 for acc1), col(q-row) = li
  float inv = 1.f / accS[0];
  float* orow = O + ((size_t)(b * SQ + i0g + li) * 1024 + h * 64);
#pragma unroll
  for (int g = 0; g < 4; ++g) {
    f32x4 o0, o1;
#pragma unroll
    for (int q_ = 0; q_ < 4; ++q_) {
      o0[q_] = acc0[g * 4 + q_] * inv;
      o1[q_] = acc1[g * 4 + q_] * inv;
    }
    *(f32x4*)(orow + 8 * g + 4 * hi) = o0;
    *(f32x4*)(orow + 32 + 8 * g + 4 * hi) = o1;
  }
}

extern "C" void kernel_launch(void* const* d_in, const int* in_sizes, int n_in,
                              void* d_out, int out_size, void* d_ws, size_t ws_size,
                              hipStream_t stream) {
  (void)in_sizes; (void)n_in; (void)out_size; (void)ws_size;
  const float* x   = (const float*)d_in[0];
  const float* ctx = (const float*)d_in[1];
  const float* Wq  = (const float*)d_in[2];
  const float* Wkv = (const float*)d_in[3];
  float* out = (float*)d_out;
  char* ws = (char*)d_ws;

  u16* xb  = (u16*)(ws);                       // x bf16   [4096][1024]  8 MB
  u16* cb  = (u16*)(ws + (8ull  << 20));       // ctx bf16 [4096][1024]  8 MB
  u16* wqb = (u16*)(ws + (16ull << 20));       // Wq bf16  [1024][1024]  2 MB
  u16* wkb = (u16*)(ws + (18ull << 20));       // Wkv bf16 [2048][1024]  4 MB
  u16* q   = (u16*)(ws + (22ull << 20));       // q bf16, pre-scaled by 0.125*log2(e)
  u16* kv  = (u16*)(ws + (30ull << 20));       // kv bf16  [4096][2048] 16 MB

  cast4_f32_bf16<<<1408, 256, 0, stream>>>(
      (const float4*)x,   (ushort4*)xb,  (4096 * 1024) / 4,
      (const float4*)ctx, (ushort4*)cb,  (4096 * 1024) / 4,
      (const float4*)Wq,  (ushort4*)wqb, (1024 * 1024) / 4,
      (const float4*)Wkv, (ushort4*)wkb, (2048 * 1024) / 4);

  gemm_fused<<<768, 256, 0, stream>>>(xb, wqb, q, cb, wkb, kv, 0.125f * 1.44269504f);

  attn_kernel<<<512, 256, 0, stream>>>(q, kv, out);
}

// Round 14
// 99.156 us; speedup vs baseline: 3.3294x; 1.0057x over previous
//
#include <hip/hip_runtime.h>
#include <hip/hip_bf16.h>
#include <stdint.h>

typedef unsigned short u16;
typedef __attribute__((ext_vector_type(8))) __bf16 bf16x8;
typedef __attribute__((ext_vector_type(4))) float f32x4;
typedef __attribute__((ext_vector_type(16))) float f32x16;

#define AS1(p) ((const __attribute__((address_space(1))) void*)(p))
#define AS3(p) ((__attribute__((address_space(3))) void*)(p))

__device__ __forceinline__ u16 f2bf(float f) {
  union { float f; uint32_t u; } c; c.f = f;
  uint32_t u = c.u;
  u += 0x7fffu + ((u >> 16) & 1u);   // RTNE
  return (u16)(u >> 16);
}

__device__ __forceinline__ float exp2_fast(float x) {
  float r; asm("v_exp_f32 %0, %1" : "=v"(r) : "v"(x)); return r;
}

// ---------------- fused cast fp32 -> bf16: 4 streams, one launch ----------------
__global__ __launch_bounds__(256) void cast4_f32_bf16(
    const float4* __restrict__ s0, ushort4* __restrict__ d0, int n0,
    const float4* __restrict__ s1, ushort4* __restrict__ d1, int n1,
    const float4* __restrict__ s2, ushort4* __restrict__ d2, int n2,
    const float4* __restrict__ s3, ushort4* __restrict__ d3, int n3) {
  int bid = blockIdx.x;
  const float4* src; ushort4* dst; int n4, b0, nb;
  if (bid < 512)       { src = s0; dst = d0; n4 = n0; b0 = 0;    nb = 512; }
  else if (bid < 1024) { src = s1; dst = d1; n4 = n1; b0 = 512;  nb = 512; }
  else if (bid < 1152) { src = s2; dst = d2; n4 = n2; b0 = 1024; nb = 128; }
  else                 { src = s3; dst = d3; n4 = n3; b0 = 1152; nb = 256; }
  int stride = nb * 256;
  for (int i = (bid - b0) * 256 + threadIdx.x; i < n4; i += stride) {
    float4 v = src[i];
    ushort4 o;
    o.x = f2bf(v.x); o.y = f2bf(v.y); o.z = f2bf(v.z); o.w = f2bf(v.w);
    dst[i] = o;
  }
}

// ---------------- fused NT GEMM (q + kv), depth-2 prefetch, T2 LDS swizzle ----------------
// r14: both-sides XOR swizzle kills the 8-way fragment-read conflict (rule #21:
// linear gload_lds dest + k-chunk-permuted SOURCE + same-permuted READ).
// LDS slot (row, kc) holds global k-chunk kc ^ ((row>>1)&3); read kc = lg ^ ((row>>1)&3).
__global__ __launch_bounds__(256) void gemm_fused(const u16* __restrict__ xb,
                                                  const u16* __restrict__ wqb,
                                                  u16* __restrict__ qo,
                                                  const u16* __restrict__ cb,
                                                  const u16* __restrict__ wkb,
                                                  u16* __restrict__ kvo,
                                                  float scale_q) {
  __shared__ u16 As[3][128 * 32];
  __shared__ u16 Bs[3][128 * 32];
  const int K = 1024;
  int bid = (blockIdx.x & 7) * 96 + (blockIdx.x >> 3);
  const u16 *A, *B; u16* C; int N, bm, bn; float scale;
  if (bid < 256) { A = xb; B = wqb; C = qo;  N = 1024; bm = bid >> 3; bn = bid & 7;  scale = scale_q; }
  else { int b2 = bid - 256; A = cb; B = wkb; C = kvo; N = 2048; bm = b2 >> 4; bn = b2 & 15; scale = 1.0f; }

  int tid = threadIdx.x;
  int w = tid >> 6, l = tid & 63;
  int wr = w >> 1, wc = w & 1;
  int lr = l & 15, lg = l >> 4;

  // source k-chunk permuted by global-row bits 1-2 (= (l>>3)&3 here; seg*16 ≡ 0 mod row-bits)
  const u16* Abase = A + (size_t)(bm * 128 + (l >> 2)) * K + ((l & 3) ^ ((l >> 3) & 3)) * 8;
  const u16* Bbase = B + (size_t)(bn * 128 + (l >> 2)) * K + ((l & 3) ^ ((l >> 3) & 3)) * 8;

  f32x4 acc[4][4];
#pragma unroll
  for (int i = 0; i < 4; ++i)
#pragma unroll
    for (int j = 0; j < 4; ++j) acc[i][j] = (f32x4){0.f, 0.f, 0.f, 0.f};

#define STAGE(buf, k0)                                                              \
  {                                                                                 \
    _Pragma("unroll")                                                               \
    for (int t2 = 0; t2 < 2; ++t2) {                                                \
      int seg = w * 2 + t2;                                                         \
      __builtin_amdgcn_global_load_lds(AS1(Abase + (size_t)seg * 16 * K + (k0)),    \
                                       AS3(&As[buf][seg * 512]), 16, 0, 0);         \
      __builtin_amdgcn_global_load_lds(AS1(Bbase + (size_t)seg * 16 * K + (k0)),    \
                                       AS3(&Bs[buf][seg * 512]), 16, 0, 0);         \
    }                                                                               \
  }

  STAGE(0, 0);
  STAGE(1, 32);
  int cur = 0;
  int kswz = (lg ^ ((lr >> 1) & 3)) * 8;   // swizzled read k-offset (u16 units)
  for (int t = 0; t < 32; ++t) {
    if (t < 30) {
      int pf = cur + 2; if (pf >= 3) pf -= 3;
      STAGE(pf, (t + 2) * 32);
      asm volatile("s_waitcnt vmcnt(8)" ::: "memory");
    } else if (t == 30) {
      asm volatile("s_waitcnt vmcnt(4)" ::: "memory");
    } else {
      asm volatile("s_waitcnt vmcnt(0)" ::: "memory");
    }
    __builtin_amdgcn_s_barrier();
    bf16x8 af[4], bb[4];
#pragma unroll
    for (int i = 0; i < 4; ++i)
      af[i] = *(const bf16x8*)(&As[cur][(wr * 64 + i * 16 + lr) * 32 + kswz]);
#pragma unroll
    for (int j = 0; j < 4; ++j)
      bb[j] = *(const bf16x8*)(&Bs[cur][(wc * 64 + j * 16 + lr) * 32 + kswz]);
    asm volatile("s_waitcnt lgkmcnt(0)" ::: "memory");
    __builtin_amdgcn_sched_barrier(0);
#pragma unroll
    for (int i = 0; i < 4; ++i)
#pragma unroll
      for (int j = 0; j < 4; ++j)
        acc[i][j] = __builtin_amdgcn_mfma_f32_16x16x32_bf16(af[i], bb[j], acc[i][j], 0, 0, 0);
    __builtin_amdgcn_s_barrier();
    if (++cur == 3) cur = 0;
  }
#undef STAGE

#pragma unroll
  for (int i = 0; i < 4; ++i)
#pragma unroll
    for (int j = 0; j < 4; ++j)
#pragma unroll
      for (int r = 0; r < 4; ++r) {
        int row = bm * 128 + wr * 64 + i * 16 + lg * 4 + r;
        int col = bn * 128 + wc * 64 + j * 16 + lr;
        C[(size_t)row * N + col] = f2bf(acc[i][j][r] * scale);
      }
}

// ---------------- flash attention: KVBLK=128, single-buffer Vt, ones-MFMA row-sum ----------------
// grid = 512 blocks, 256 thr (4 waves x 32 q-rows). __launch_bounds__(256,2): the live set
// (~200 unified VGPR+AGPR) requires the 256-reg budget — (256,3) spills catastrophically (r12).
#define SQ 2048
#define NTT 16

__global__ __launch_bounds__(256, 2) void attn_kernel(const u16* __restrict__ Q,
                                                      const u16* __restrict__ KV,
                                                      float* __restrict__ O) {
  __shared__ u16 Ks[2][128 * 64];  // [buf][j][d], 16B-block bk holds dblk = bk ^ (j&7)  32KB
  __shared__ u16 Vt[64 * 128];     // [d][j], byte = d*256 + ((j*2) ^ (((d^(d>>3))&7)<<4)) 16KB

  int wgid = (blockIdx.x & 7) * 64 + (blockIdx.x >> 3);   // bijective 8x64 XCD swizzle
  int qt = wgid & 15;
  int bh = wgid >> 4;
  int b = bh >> 4, h = bh & 15;
  int tid = threadIdx.x;
  int w = tid >> 6, l = tid & 63;
  int li = l & 31, hi = l >> 5;
  int jr = l >> 3, bk = l & 7;
  int a7 = tid & 7, jj = tid >> 3;   // V staging coords

  const u16* kbase = KV + (size_t)b * SQ * 2048 + (size_t)h * 64;
  const u16* vbase = kbase + 1024;
  int i0g = qt * 128 + w * 32;
  const u16* qrow = Q + (size_t)(b * SQ + i0g + li) * 1024 + h * 64;

  bf16x8 qf0 = *(const bf16x8*)(qrow + 0  + hi * 8);
  bf16x8 qf1 = *(const bf16x8*)(qrow + 16 + hi * 8);
  bf16x8 qf2 = *(const bf16x8*)(qrow + 32 + hi * 8);
  bf16x8 qf3 = *(const bf16x8*)(qrow + 48 + hi * 8);

  union { u16 u[8]; bf16x8 v; } onesu;
#pragma unroll
  for (int e = 0; e < 8; ++e) onesu.u[e] = 0x3F80;   // bf16 1.0
  bf16x8 ones = onesu.v;

  // prologue: stage K tile 0 (128 rows, 4 gload_lds/thread); V tile 0 -> regs
#pragma unroll
  for (int c = 0; c < 4; ++c) {
    const u16* gk = kbase + (size_t)(c * 32 + w * 8 + jr) * 2048 + ((bk ^ jr) * 8);
    __builtin_amdgcn_global_load_lds(AS1(gk), AS3(&Ks[0][c * 2048 + w * 512]), 16, 0, 0);
  }
  uint4 vrA = *(const uint4*)(vbase + (size_t)(jj +  0) * 2048 + a7 * 8);
  uint4 vrB = *(const uint4*)(vbase + (size_t)(jj + 32) * 2048 + a7 * 8);
  uint4 vrC = *(const uint4*)(vbase + (size_t)(jj + 64) * 2048 + a7 * 8);
  uint4 vrD = *(const uint4*)(vbase + (size_t)(jj + 96) * 2048 + a7 * 8);

  float m_run = -1e30f;
  f32x16 acc0, acc1, accS, zz;
#pragma unroll
  for (int r = 0; r < 16; ++r) { acc0[r] = 0.f; acc1[r] = 0.f; accS[r] = 0.f; zz[r] = 0.f; }

  int swk = (li & 7) << 4;
  int sw0 = ((li ^ (li >> 3)) & 7) << 4;                 // Vt read swizzle, d = li
  int sw1 = (((32 + li) ^ ((32 + li) >> 3)) & 7) << 4;   // d = 32+li

  for (int t = 0; t < NTT; ++t) {
    u16* Ksc = (u16*)Ks[t & 1];
    char* Vtc = (char*)Vt;
    __syncthreads();   // K(t),V(t) landed (vmcnt drain); all waves' PV(t-1) reads of Vt done
    // ---- V transpose-store: 32 scalar b16 (2-way bank max)
    {
      const u16* pA = (const u16*)&vrA;
      const u16* pB = (const u16*)&vrB;
      const u16* pC = (const u16*)&vrC;
      const u16* pD = (const u16*)&vrD;
#pragma unroll
      for (int e = 0; e < 8; ++e) {
        int dbyte = (a7 * 8 + e) * 256, sw = (e ^ a7) << 4;
        *(u16*)(Vtc + dbyte + (((jj * 2) +   0) ^ sw)) = pA[e];
        *(u16*)(Vtc + dbyte + (((jj * 2) +  64) ^ sw)) = pB[e];
        *(u16*)(Vtc + dbyte + (((jj * 2) + 128) ^ sw)) = pC[e];
        *(u16*)(Vtc + dbyte + (((jj * 2) + 192) ^ sw)) = pD[e];
      }
    }
    asm volatile("s_waitcnt lgkmcnt(0)" ::: "memory");   // my ds_writes committed
    __builtin_amdgcn_s_barrier();                        // Vt visible (no vmcnt drain)
    // ---- prefetch tile t+1 (rides through compute; drained by next top-sync)
    if (t + 1 < NTT) {
      int j0n = (t + 1) * 128;
      u16* Ksn = (u16*)Ks[(t + 1) & 1];
#pragma unroll
      for (int c = 0; c < 4; ++c) {
        const u16* gk = kbase + (size_t)(j0n + c * 32 + w * 8 + jr) * 2048 + ((bk ^ jr) * 8);
        __builtin_amdgcn_global_load_lds(AS1(gk), AS3(&Ksn[c * 2048 + w * 512]), 16, 0, 0);
      }
      vrA = *(const uint4*)(vbase + (size_t)(j0n + jj +  0) * 2048 + a7 * 8);
      vrB = *(const uint4*)(vbase + (size_t)(j0n + jj + 32) * 2048 + a7 * 8);
      vrC = *(const uint4*)(vbase + (size_t)(j0n + jj + 64) * 2048 + a7 * 8);
      vrD = *(const uint4*)(vbase + (size_t)(j0n + jj + 96) * 2048 + a7 * 8);
    }
    // ---- swapped QK^T: 16 MFMAs, 4 independent chains
    f32x16 s0, s1, s2, s3;
    __builtin_amdgcn_s_setprio(1);
#define QKT1(sv, JB)                                                             \
    {                                                                            \
      const char* kr = (const char*)Ksc + ((JB) * 32 + li) * 128;                \
      bf16x8 kk;                                                                 \
      kk = *(const bf16x8*)(kr + ((0  + hi * 16) ^ swk));                        \
      sv = __builtin_amdgcn_mfma_f32_32x32x16_bf16(kk, qf0, zz, 0, 0, 0);        \
      kk = *(const bf16x8*)(kr + ((32 + hi * 16) ^ swk));                        \
      sv = __builtin_amdgcn_mfma_f32_32x32x16_bf16(kk, qf1, sv, 0, 0, 0);        \
      kk = *(const bf16x8*)(kr + ((64 + hi * 16) ^ swk));                        \
      sv = __builtin_amdgcn_mfma_f32_32x32x16_bf16(kk, qf2, sv, 0, 0, 0);        \
      kk = *(const bf16x8*)(kr + ((96 + hi * 16) ^ swk));                        \
      sv = __builtin_amdgcn_mfma_f32_32x32x16_bf16(kk, qf3, sv, 0, 0, 0);        \
    }
    QKT1(s0, 0)
    QKT1(s1, 1)
    QKT1(s2, 2)
    QKT1(s3, 3)
#undef QKT1
    __builtin_amdgcn_s_setprio(0);
    // ---- ONE max-reduce over 64 values (v_max3-friendly pairs)
    float pm = fmaxf(s0[14], s0[15]);
#pragma unroll
    for (int r = 0; r < 14; r += 2) pm = fmaxf(fmaxf(pm, s0[r]), s0[r + 1]);
#pragma unroll
    for (int r = 0; r < 16; r += 2) pm = fmaxf(fmaxf(pm, s1[r]), s1[r + 1]);
#pragma unroll
    for (int r = 0; r < 16; r += 2) pm = fmaxf(fmaxf(pm, s2[r]), s2[r + 1]);
#pragma unroll
    for (int r = 0; r < 16; r += 2) pm = fmaxf(fmaxf(pm, s3[r]), s3[r + 1]);
    pm = fmaxf(pm, __shfl_xor(pm, 32));
    if (!__all(pm <= m_run + 8.0f)) {
      float mnew = fmaxf(m_run, pm);
      float esc = exp2_fast(m_run - mnew);
      m_run = mnew;
      accS[0] *= esc;   // only reg 0 of accS is ever read
#pragma unroll
      for (int r = 0; r < 16; ++r) { acc0[r] *= esc; acc1[r] *= esc; }
    }
    // ---- exp in place (64 independent; no sum chain — accS handles l)
#pragma unroll
    for (int r = 0; r < 16; ++r) s0[r] = exp2_fast(s0[r] - m_run);
#pragma unroll
    for (int r = 0; r < 16; ++r) s1[r] = exp2_fast(s1[r] - m_run);
#pragma unroll
    for (int r = 0; r < 16; ++r) s2[r] = exp2_fast(s2[r] - m_run);
#pragma unroll
    for (int r = 0; r < 16; ++r) s3[r] = exp2_fast(s3[r] - m_run);
    // ---- pack P -> bf16 A-frag layout (cvt_pk + permlane32_swap), 4 groups of 8 words
    unsigned pw[32];
#pragma unroll
    for (int i2 = 0; i2 < 8; ++i2) {
      asm("v_cvt_pk_bf16_f32 %0, %1, %2" : "=v"(pw[i2])      : "v"(s0[2 * i2]), "v"(s0[2 * i2 + 1]));
      asm("v_cvt_pk_bf16_f32 %0, %1, %2" : "=v"(pw[8 + i2])  : "v"(s1[2 * i2]), "v"(s1[2 * i2 + 1]));
      asm("v_cvt_pk_bf16_f32 %0, %1, %2" : "=v"(pw[16 + i2]) : "v"(s2[2 * i2]), "v"(s2[2 * i2 + 1]));
      asm("v_cvt_pk_bf16_f32 %0, %1, %2" : "=v"(pw[24 + i2]) : "v"(s3[2 * i2]), "v"(s3[2 * i2 + 1]));
    }
#pragma unroll
    for (int gB = 0; gB < 4; ++gB) {
      int o = gB * 8;
      asm volatile("v_permlane32_swap_b32 %0, %1" : "+v"(pw[o + 0]), "+v"(pw[o + 2]));
      asm volatile("v_permlane32_swap_b32 %0, %1" : "+v"(pw[o + 1]), "+v"(pw[o + 3]));
      asm volatile("v_permlane32_swap_b32 %0, %1" : "+v"(pw[o + 4]), "+v"(pw[o + 6]));
      asm volatile("v_permlane32_swap_b32 %0, %1" : "+v"(pw[o + 5]), "+v"(pw[o + 7]));
    }
    // ---- PV as O^T (16 MFMAs) + row-sum accS (8 MFMAs, A=ones)
    __builtin_amdgcn_s_setprio(1);
#pragma unroll
    for (int jsp = 0; jsp < 8; ++jsp) {
      uint4 ufr;
      ufr.x = pw[jsp * 4 + 0]; ufr.y = pw[jsp * 4 + 1];
      ufr.z = pw[jsp * 4 + 2]; ufr.w = pw[jsp * 4 + 3];
      bf16x8 pa = *(bf16x8*)&ufr;
      int jbyte = jsp * 32 + hi * 16;
      bf16x8 v0 = *(const bf16x8*)(Vtc + li * 256 + (jbyte ^ sw0));
      bf16x8 v1 = *(const bf16x8*)(Vtc + (32 + li) * 256 + (jbyte ^ sw1));
      acc0 = __builtin_amdgcn_mfma_f32_32x32x16_bf16(v0, pa, acc0, 0, 0, 0);
      acc1 = __builtin_amdgcn_mfma_f32_32x32x16_bf16(v1, pa, acc1, 0, 0, 0);
      accS = __builtin_amdgcn_mfma_f32_32x32x16_bf16(ones, pa, accS, 0, 0, 0);
    }
    __builtin_amdgcn_s_setprio(0);
  }
  // ---- epilogue: O^T layout, d = 8g + 4hi + r (+32 for acc1), col(q-row) = li
  float inv = 1.f / accS[0];
  float* orow = O + ((size_t)(b * SQ + i0g + li) * 1024 + h * 64);
#pragma unroll
  for (int g = 0; g < 4; ++g) {
    f32x4 o0, o1;
#pragma unroll
    for (int q_ = 0; q_ < 4; ++q_) {
      o0[q_] = acc0[g * 4 + q_] * inv;
      o1[q_] = acc1[g * 4 + q_] * inv;
    }
    *(f32x4*)(orow + 8 * g + 4 * hi) = o0;
    *(f32x4*)(orow + 32 + 8 * g + 4 * hi) = o1;
  }
}

extern "C" void kernel_launch(void* const* d_in, const int* in_sizes, int n_in,
                              void* d_out, int out_size, void* d_ws, size_t ws_size,
                              hipStream_t stream) {
  (void)in_sizes; (void)n_in; (void)out_size; (void)ws_size;
  const float* x   = (const float*)d_in[0];
  const float* ctx = (const float*)d_in[1];
  const float* Wq  = (const float*)d_in[2];
  const float* Wkv = (const float*)d_in[3];
  float* out = (float*)d_out;
  char* ws = (char*)d_ws;

  u16* xb  = (u16*)(ws);                       // x bf16   [4096][1024]  8 MB
  u16* cb  = (u16*)(ws + (8ull  << 20));       // ctx bf16 [4096][1024]  8 MB
  u16* wqb = (u16*)(ws + (16ull << 20));       // Wq bf16  [1024][1024]  2 MB
  u16* wkb = (u16*)(ws + (18ull << 20));       // Wkv bf16 [2048][1024]  4 MB
  u16* q   = (u16*)(ws + (22ull << 20));       // q bf16, pre-scaled by 0.125*log2(e)
  u16* kv  = (u16*)(ws + (30ull << 20));       // kv bf16  [4096][2048] 16 MB

  cast4_f32_bf16<<<1408, 256, 0, stream>>>(
      (const float4*)x,   (ushort4*)xb,  (4096 * 1024) / 4,
      (const float4*)ctx, (ushort4*)cb,  (4096 * 1024) / 4,
      (const float4*)Wq,  (ushort4*)wqb, (1024 * 1024) / 4,
      (const float4*)Wkv, (ushort4*)wkb, (2048 * 1024) / 4);

  gemm_fused<<<768, 256, 0, stream>>>(xb, wqb, q, cb, wkb, kv, 0.125f * 1.44269504f);

  attn_kernel<<<512, 256, 0, stream>>>(q, kv, out);
}